// Round 3
// baseline (14438.640 us; speedup 1.0000x reference)
//
#include <hip/hip_runtime.h>
#include <hip/hip_bf16.h>

// LSTM N=64, T=512, D=1024, H=1024 — persistent cooperative kernel, take 2.
// Grid 256 WGs (1/CU) = 4 row-groups(16 rows) x 64 col-groups(16 h-cols).
// Wave w owns K-slice [512w,512w+512) of K=2048 ([x_t | h_{t-1}]):
//   waves 0,1 = x-half (independent of recurrence, runs ahead)
//   waves 2,3 = h-half (poll epoch counter, then stage h)
// Weights: 64 A-cols x 512 K per wave in 256 VGPRs (MFMA B-fragments).
// LDS: Abuf chunked (2 x 256 K) = 33.8 KB + red 17.4 KB = 51.2 KB < 64 KB.
// Fallback: if hipLaunchCooperativeKernel errors, run round-1 per-step loop.

#define T_T 512
#define KTOT 2048
#define NWG 256

typedef short bf16x8 __attribute__((ext_vector_type(8)));
typedef float f32x4 __attribute__((ext_vector_type(4)));
union B8U { uint4 u; bf16x8 v; };
union P4 { __hip_bfloat16 h[4]; uint2 u; };

__global__ __launch_bounds__(256) void prep_weights(const float* __restrict__ Wx,
                                                    const float* __restrict__ Wh,
                                                    __hip_bfloat16* __restrict__ Wt) {
  __shared__ float tile[64][65];
  int kb = blockIdx.x & 31;
  int cb = blockIdx.x >> 5;
  int k0 = kb << 6, c0 = cb << 6;
  const float* W = (k0 < 1024) ? Wx : Wh;
  int kr0 = k0 & 1023;
  int tid = threadIdx.x;
  int f4 = tid & 15;
  int i0 = tid >> 4;
  for (int p = 0; p < 4; ++p) {
    int i = i0 + (p << 4);
    float4 v = *(const float4*)(W + (size_t)(kr0 + i) * 4096 + c0 + (f4 << 2));
    tile[(f4 << 2) + 0][i] = v.x;
    tile[(f4 << 2) + 1][i] = v.y;
    tile[(f4 << 2) + 2][i] = v.z;
    tile[(f4 << 2) + 3][i] = v.w;
  }
  __syncthreads();
  for (int p = 0; p < 16; ++p) {
    int idx = (p << 8) + tid;
    int kl = idx & 63, cl = idx >> 6;
    Wt[(size_t)(c0 + cl) * KTOT + k0 + kl] = __float2bfloat16(tile[cl][kl]);
  }
}

// cbuf[0] doubles as the epoch counter (coop path); fallback path uses cbuf as c-state.
__global__ __launch_bounds__(256) void prep_state(const float* __restrict__ h0,
                                                  __hip_bfloat16* __restrict__ hb,
                                                  float* __restrict__ cbuf) {
  int i = blockIdx.x * 256 + threadIdx.x;   // 65536
  hb[i] = __float2bfloat16(h0[i]);
  cbuf[i] = 0.f;
}

__device__ inline uint2 cvt4(float4 a) {
  P4 p;
  p.h[0] = __float2bfloat16(a.x); p.h[1] = __float2bfloat16(a.y);
  p.h[2] = __float2bfloat16(a.z); p.h[3] = __float2bfloat16(a.w);
  return p.u;
}

__global__ __launch_bounds__(256, 1) void lstm_persist(
    const float* __restrict__ x, const float* __restrict__ bias,
    const __hip_bfloat16* __restrict__ Wt,
    __hip_bfloat16* __restrict__ hb0, __hip_bfloat16* __restrict__ hb1,
    float* __restrict__ out, unsigned int* cnt)
{
  // stride 264 bf16 = 528 B: 16B-aligned, bank shift 4/row -> 2-way (free)
  __shared__ __align__(16) __hip_bfloat16 Abuf[4][16][264];
  __shared__ float red[4][4][16][17];

  const int tid = threadIdx.x;
  const int cg = blockIdx.x & 63;
  const int rg = blockIdx.x >> 6;
  const int rows0 = rg << 4;
  const int lane = tid & 63;
  const int wv = tid >> 6;              // K-slice owner
  const int mcol = lane & 15;
  const int q = lane >> 4;

  // ---- this wave's weights: 4 gates x 16 k-steps of B-fragments (256 VGPRs) ----
  bf16x8 wfrag[4][16];
  #pragma unroll
  for (int g = 0; g < 4; ++g) {
    const __hip_bfloat16* wp =
        Wt + ((size_t)(g * 1024 + cg * 16 + mcol)) * KTOT + wv * 512 + q * 8;
    #pragma unroll
    for (int kk = 0; kk < 16; ++kk) {
      B8U b; b.u = *(const uint4*)(wp + kk * 32);
      wfrag[g][kk] = b.v;
    }
  }

  const int er = tid >> 4, ej = tid & 15;
  const int hcol = (cg << 4) + ej;
  const int grow = rows0 + er;
  const float b_i = bias[hcol], b_f = bias[1024 + hcol];
  const float b_o = bias[2048 + hcol], b_g = bias[3072 + hcol];
  float c = 0.f;

  for (int t = 0; t < T_T; ++t) {
    f32x4 a0 = {0.f, 0.f, 0.f, 0.f}, a1 = a0, a2 = a0, a3 = a0;
    #pragma unroll
    for (int ch = 0; ch < 2; ++ch) {
      // ---- stage this wave's 16x256 chunk ----
      if (wv < 2) {
        const int ks = wv * 512 + ch * 256;
        #pragma unroll
        for (int p = 0; p < 16; ++p) {
          float4 v = *(const float4*)(x + ((size_t)(rows0 + p) * T_T + t) * 1024 + ks + lane * 4);
          *(uint2*)&Abuf[wv][p][lane * 4] = cvt4(v);
        }
      } else {
        if (t > 0 && ch == 0) {
          const unsigned target = (unsigned)t * (unsigned)NWG;
          while (__hip_atomic_load(cnt, __ATOMIC_RELAXED, __HIP_MEMORY_SCOPE_AGENT) < target)
            __builtin_amdgcn_s_sleep(1);
          __builtin_amdgcn_fence(__ATOMIC_ACQUIRE, "agent");
        }
        const __hip_bfloat16* hbsrc =
            ((t & 1) ? hb1 : hb0) + (size_t)rows0 * 1024 + (wv - 2) * 512 + ch * 256 + lane * 4;
        #pragma unroll
        for (int p = 0; p < 16; ++p) {
          uint2 v = *(const uint2*)(hbsrc + p * 1024);
          *(uint2*)&Abuf[wv][p][lane * 4] = v;
        }
      }
      // ---- MFMA: 8 k-steps x 4 gates on this chunk ----
      #pragma unroll
      for (int kk = 0; kk < 8; ++kk) {
        B8U a; a.u = *(const uint4*)&Abuf[wv][mcol][kk * 32 + q * 8];
        const int kw = ch * 8 + kk;
        a0 = __builtin_amdgcn_mfma_f32_16x16x32_bf16(a.v, wfrag[0][kw], a0, 0, 0, 0);
        a1 = __builtin_amdgcn_mfma_f32_16x16x32_bf16(a.v, wfrag[1][kw], a1, 0, 0, 0);
        a2 = __builtin_amdgcn_mfma_f32_16x16x32_bf16(a.v, wfrag[2][kw], a2, 0, 0, 0);
        a3 = __builtin_amdgcn_mfma_f32_16x16x32_bf16(a.v, wfrag[3][kw], a3, 0, 0, 0);
      }
    }
    #pragma unroll
    for (int i = 0; i < 4; ++i) {
      red[wv][0][(q << 2) + i][mcol] = a0[i];
      red[wv][1][(q << 2) + i][mcol] = a1[i];
      red[wv][2][(q << 2) + i][mcol] = a2[i];
      red[wv][3][(q << 2) + i][mcol] = a3[i];
    }
    __syncthreads();

    float s_i = red[0][0][er][ej] + red[1][0][er][ej] + red[2][0][er][ej] + red[3][0][er][ej] + b_i;
    float s_f = red[0][1][er][ej] + red[1][1][er][ej] + red[2][1][er][ej] + red[3][1][er][ej] + b_f;
    float s_o = red[0][2][er][ej] + red[1][2][er][ej] + red[2][2][er][ej] + red[3][2][er][ej] + b_o;
    float s_g = red[0][3][er][ej] + red[1][3][er][ej] + red[2][3][er][ej] + red[3][3][er][ej] + b_g;
    float iv = 1.f / (1.f + expf(-s_i));
    float fv = 1.f / (1.f + expf(-s_f));
    float ov = 1.f / (1.f + expf(-s_o));
    float gv = tanhf(s_g);
    c = fv * c + iv * gv;
    float hv = ov * tanhf(c);
    out[((size_t)grow * T_T + t) * 1024 + hcol] = hv;
    ((t & 1) ? hb0 : hb1)[(size_t)grow * 1024 + hcol] = __float2bfloat16(hv);
    __syncthreads();   // all waves' stores drained (vmcnt(0)) before publish
    if (tid == 0)
      __hip_atomic_fetch_add(cnt, 1u, __ATOMIC_RELEASE, __HIP_MEMORY_SCOPE_AGENT);
  }
}

// ---------------- fallback: round-1 per-step kernel (proven correct) ----------------
__global__ __launch_bounds__(256) void lstm_step(
    const float* __restrict__ x, const float* __restrict__ bias,
    const __hip_bfloat16* __restrict__ Wt,
    const __hip_bfloat16* __restrict__ hprev,
    __hip_bfloat16* __restrict__ hnext,
    float* __restrict__ cbuf, float* __restrict__ out, int t)
{
  __shared__ __align__(16) __hip_bfloat16 Alds[16][1032];
  __shared__ float gtile[4][16][17];
  const int tid = threadIdx.x;
  const int cgrp = blockIdx.x & 63;
  const int bg = blockIdx.x >> 6;
  const int rows0 = bg << 4;
  const int lane = tid & 63;
  const int wv = tid >> 6;
  const int mcol = lane & 15;
  const int q = lane >> 4;
  f32x4 acc = {0.f, 0.f, 0.f, 0.f};
  const size_t wrow = ((size_t)(wv << 10) + (cgrp << 4) + mcol) * (size_t)KTOT;
  {
    const float4* x4 = (const float4*)x;
    for (int p = 0; p < 16; ++p) {
      int idx = (p << 8) + tid;
      int r = idx >> 8;
      int c4 = idx & 255;
      float4 v = x4[((size_t)(rows0 + r) * T_T + t) * 256 + c4];
      *(uint2*)&Alds[r][c4 << 2] = cvt4(v);
    }
  }
  __syncthreads();
  #pragma unroll 4
  for (int kk = 0; kk < 32; ++kk) {
    B8U a, b;
    a.u = *(const uint4*)&Alds[mcol][(kk << 5) + (q << 3)];
    b.u = *(const uint4*)(Wt + wrow + (kk << 5) + (q << 3));
    acc = __builtin_amdgcn_mfma_f32_16x16x32_bf16(a.v, b.v, acc, 0, 0, 0);
  }
  __syncthreads();
  {
    const uint4* h4 = (const uint4*)hprev;
    for (int p = 0; p < 8; ++p) {
      int idx = (p << 8) + tid;
      int r = idx >> 7;
      int c8 = idx & 127;
      uint4 v = h4[(size_t)(rows0 + r) * 128 + c8];
      *(uint4*)&Alds[r][c8 << 3] = v;
    }
  }
  __syncthreads();
  #pragma unroll 4
  for (int kk = 0; kk < 32; ++kk) {
    B8U a, b;
    a.u = *(const uint4*)&Alds[mcol][(kk << 5) + (q << 3)];
    b.u = *(const uint4*)(Wt + wrow + 1024 + (kk << 5) + (q << 3));
    acc = __builtin_amdgcn_mfma_f32_16x16x32_bf16(a.v, b.v, acc, 0, 0, 0);
  }
  #pragma unroll
  for (int i = 0; i < 4; ++i)
    gtile[wv][(q << 2) + i][mcol] = acc[i];
  __syncthreads();
  {
    int r = tid >> 4, j = tid & 15;
    int hcol = (cgrp << 4) + j;
    float av_i = gtile[0][r][j] + bias[hcol];
    float av_f = gtile[1][r][j] + bias[1024 + hcol];
    float av_o = gtile[2][r][j] + bias[2048 + hcol];
    float av_g = gtile[3][r][j] + bias[3072 + hcol];
    float iv = 1.f / (1.f + expf(-av_i));
    float fv = 1.f / (1.f + expf(-av_f));
    float ov = 1.f / (1.f + expf(-av_o));
    float gv = tanhf(av_g);
    int rg2 = rows0 + r;
    size_t cidx = (size_t)rg2 * 1024 + hcol;
    float cn = fv * cbuf[cidx] + iv * gv;
    cbuf[cidx] = cn;
    float hv = ov * tanhf(cn);
    out[((size_t)rg2 * T_T + t) * 1024 + hcol] = hv;
    hnext[cidx] = __float2bfloat16(hv);
  }
}

extern "C" void kernel_launch(void* const* d_in, const int* in_sizes, int n_in,
                              void* d_out, int out_size, void* d_ws, size_t ws_size,
                              hipStream_t stream) {
  (void)in_sizes; (void)n_in; (void)out_size; (void)ws_size;
  const float* x    = (const float*)d_in[0];
  const float* h0   = (const float*)d_in[1];
  const float* Wx   = (const float*)d_in[2];
  const float* Wh   = (const float*)d_in[3];
  const float* bias = (const float*)d_in[4];
  float* out = (float*)d_out;

  char* ws = (char*)d_ws;
  __hip_bfloat16* Wt  = (__hip_bfloat16*)ws;                          // 16 MB
  __hip_bfloat16* hb0 = (__hip_bfloat16*)(ws + (size_t)16 * 1024 * 1024);   // 128 KB
  __hip_bfloat16* hb1 = hb0 + 64 * 1024;                              // 128 KB
  float* cbuf = (float*)(hb1 + 64 * 1024);                            // 256 KB; [0] = epoch cnt
  unsigned int* cnt = (unsigned int*)cbuf;                            // alias (paths disjoint)

  hipLaunchKernelGGL(prep_weights, dim3(2048), dim3(256), 0, stream, Wx, Wh, Wt);
  hipLaunchKernelGGL(prep_state, dim3(256), dim3(256), 0, stream, h0, hb0, cbuf);

  void* args[] = { (void*)&x, (void*)&bias, (void*)&Wt, (void*)&hb0,
                   (void*)&hb1, (void*)&out, (void*)&cnt };
  hipError_t rc = hipLaunchCooperativeKernel((const void*)lstm_persist, dim3(NWG),
                                             dim3(256), args, 0, stream);
  if (rc != hipSuccess) {
    // deterministic fallback: per-step loop (c-state in cbuf, zeroed by prep_state)
    for (int t = 0; t < T_T; ++t) {
      __hip_bfloat16* hp = (t & 1) ? hb1 : hb0;
      __hip_bfloat16* hn = (t & 1) ? hb0 : hb1;
      hipLaunchKernelGGL(lstm_step, dim3(256), dim3(256), 0, stream,
                         x, bias, Wt, hp, hn, cbuf, out, t);
    }
  }
}